// Round 18
// baseline (189.683 us; speedup 1.0000x reference)
//
#include <hip/hip_runtime.h>

#define DM 128
#define DFF 512
#define CLAMP_V 5.0f
#define LN_EPS 1e-5f

typedef __attribute__((ext_vector_type(8))) short bf16x8;
typedef __attribute__((ext_vector_type(4))) float f32x4;
typedef __attribute__((ext_vector_type(2))) float f32x2;

__device__ __forceinline__ float b2f(ushort u) {
  union { uint u; float f; } x; x.u = ((uint)u) << 16; return x.f;
}
__device__ __forceinline__ ushort f2b(float f) {
  union { float f; uint u; } x; x.f = f;
  uint r = x.u + 0x7FFFu + ((x.u >> 16) & 1u);
  return (ushort)(r >> 16);
}
__device__ __forceinline__ f32x2 upk2(uint w) {
  union { uint u; float f; } a, b;
  a.u = w << 16; b.u = w & 0xFFFF0000u;
  f32x2 r; r[0] = a.f; r[1] = b.f; return r;
}

// ---------------- fused prep: feat cast + weight cast + degree count ----------------
__global__ void k_prep(const float* __restrict__ feat,
                       const float* __restrict__ wq, const float* __restrict__ wk,
                       const float* __restrict__ wv, const float* __restrict__ wo,
                       const float* __restrict__ w1, const float* __restrict__ w2,
                       ushort* __restrict__ feat_bf, ushort* __restrict__ wbf,
                       const int* __restrict__ dst, int* __restrict__ deg,
                       int nf4, int castBlocks, int E) {
  if ((int)blockIdx.x >= castBlocks) {
    int e = ((int)blockIdx.x - castBlocks) * 256 + threadIdx.x;
    if (e < E) atomicAdd(&deg[dst[e]], 1);
    return;
  }
  int i = blockIdx.x * 256 + threadIdx.x;
  if (i < nf4) {
    float4 v = *reinterpret_cast<const float4*>(feat + i * 4);
    ushort4 o; o.x = f2b(v.x); o.y = f2b(v.y); o.z = f2b(v.z); o.w = f2b(v.w);
    *reinterpret_cast<ushort4*>(feat_bf + i * 4) = o;
    return;
  }
  int i4 = (i - nf4) * 4;
  if (i4 >= 196608) return;
  const float* s; int o;
  if      (i4 < 16384)  { s = wq; o = i4; }
  else if (i4 < 32768)  { s = wk; o = i4 - 16384; }
  else if (i4 < 49152)  { s = wv; o = i4 - 32768; }
  else if (i4 < 65536)  { s = wo; o = i4 - 49152; }
  else if (i4 < 131072) { s = w1; o = i4 - 65536; }
  else                  { s = w2; o = i4 - 131072; }
  float4 v = *reinterpret_cast<const float4*>(s + o);
  ushort4 u; u.x = f2b(v.x); u.y = f2b(v.y); u.z = f2b(v.z); u.w = f2b(v.w);
  *reinterpret_cast<ushort4*>(wbf + i4) = u;
}

#define SC_EPB 1024

// single-kernel exclusive scan; also zeroes cur, writes off[n]=E
__global__ __launch_bounds__(256) void k_scan(const int* __restrict__ deg,
                                              int* __restrict__ off,
                                              int* __restrict__ cur,
                                              int n, int E) {
  __shared__ int sh[256];
  __shared__ int wsum[4];
  const int t = threadIdx.x;
  const int bstart = blockIdx.x * SC_EPB;

  int gs = 0;
  for (int base = t * 4; base < bstart; base += SC_EPB) {
    int4 v = *reinterpret_cast<const int4*>(deg + base);
    gs += v.x + v.y + v.z + v.w;
  }
  #pragma unroll
  for (int m = 1; m < 64; m <<= 1) gs += __shfl_xor(gs, m);
  if ((t & 63) == 0) wsum[t >> 6] = gs;
  __syncthreads();
  int gadd = wsum[0] + wsum[1] + wsum[2] + wsum[3];
  __syncthreads();

  int base = bstart + t * 4;
  int4 v = {0, 0, 0, 0};
  if (base + 3 < n) {
    v = *reinterpret_cast<const int4*>(deg + base);
  } else {
    if (base     < n) v.x = deg[base];
    if (base + 1 < n) v.y = deg[base + 1];
    if (base + 2 < n) v.z = deg[base + 2];
    if (base + 3 < n) v.w = deg[base + 3];
  }
  int s = v.x + v.y + v.z + v.w;
  sh[t] = s;
  __syncthreads();
  #pragma unroll
  for (int d = 1; d < 256; d <<= 1) {
    int x = 0;
    if (t >= d) x = sh[t - d];
    __syncthreads();
    sh[t] += x;
    __syncthreads();
  }
  int ex = sh[t] - s + gadd;
  if (base + 3 < n) {
    int4 o; o.x = ex; o.y = ex + v.x; o.z = ex + v.x + v.y; o.w = ex + v.x + v.y + v.z;
    *reinterpret_cast<int4*>(off + base) = o;
    int4 z = {0, 0, 0, 0};
    *reinterpret_cast<int4*>(cur + base) = z;
  } else {
    if (base     < n) { off[base]     = ex;                    cur[base]     = 0; }
    if (base + 1 < n) { off[base + 1] = ex + v.x;              cur[base + 1] = 0; }
    if (base + 2 < n) { off[base + 2] = ex + v.x + v.y;        cur[base + 2] = 0; }
    if (base + 3 < n) { off[base + 3] = ex + v.x + v.y + v.z;  cur[base + 3] = 0; }
  }
  if (blockIdx.x == 0 && t == 0) off[n] = E;
}

// standalone scatter (0 LDS, full occupancy)
__global__ void k_scatter(const int* __restrict__ src, const int* __restrict__ dst,
                          const int* __restrict__ off, int* __restrict__ cur,
                          int* __restrict__ csr, int E) {
  int e = blockIdx.x * blockDim.x + threadIdx.x;
  if (e < E) {
    int d = dst[e];
    int p = off[d] + atomicAdd(&cur[d], 1);
    csr[p] = src[e];
  }
}

// =====================================================================
// k_qkv: one-tile-per-block GEMM, QKV split output. 512 thr, 2 blk/CU.
// =====================================================================
__global__ __launch_bounds__(512, 2) void k_qkv(
    const ushort* __restrict__ A, const ushort* __restrict__ W,
    ushort* __restrict__ Cb, ushort* __restrict__ Cb2, int M)
{
  __shared__ ushort As[128 * 128];
  __shared__ ushort Bs[128 * 128];

  const int tid = threadIdx.x;
  const int wv = tid >> 6, ln = tid & 63;
  const int bnb = blockIdx.x;
  const int mbase = blockIdx.y * 128;
  const int wrow = (wv >> 2) * 64, wcol = (wv & 3) * 32;
  const int o_base = tid * 16;

  #pragma unroll
  for (int is = 0; is < 4; ++is) {
    int o = is * 8192 + o_base;
    int row = o >> 8;
    int c = ((o >> 4) & 15) ^ (row & 15);
    int gr = min(mbase + row, M - 1);
    const ushort* sA = A + (size_t)gr * 128 + c * 8;
    __builtin_amdgcn_global_load_lds(
        (const __attribute__((address_space(1))) void*)sA,
        (__attribute__((address_space(3))) void*)((char*)As + is * 8192 + wv * 1024),
        16, 0, 0);
    const ushort* sB = W + (size_t)(bnb * 128 + row) * 128 + c * 8;
    __builtin_amdgcn_global_load_lds(
        (const __attribute__((address_space(1))) void*)sB,
        (__attribute__((address_space(3))) void*)((char*)Bs + is * 8192 + wv * 1024),
        16, 0, 0);
  }
  __syncthreads();

  f32x4 acc[4][2] = {};
  const char* AsB = (const char*)As;
  const char* BsB = (const char*)Bs;
  #pragma unroll
  for (int kk = 0; kk < 4; ++kk) {
    bf16x8 af[4], bfr[2];
    #pragma unroll
    for (int m = 0; m < 4; ++m) {
      int r = wrow + m * 16 + (ln & 15);
      int c = kk * 4 + (ln >> 4);
      af[m] = *reinterpret_cast<const bf16x8*>(AsB + r * 256 + ((c ^ (r & 15)) << 4));
    }
    #pragma unroll
    for (int n = 0; n < 2; ++n) {
      int r = wcol + n * 16 + (ln & 15);
      int c = kk * 4 + (ln >> 4);
      bfr[n] = *reinterpret_cast<const bf16x8*>(BsB + r * 256 + ((c ^ (r & 15)) << 4));
    }
    #pragma unroll
    for (int m = 0; m < 4; ++m)
      #pragma unroll
      for (int n = 0; n < 2; ++n)
        acc[m][n] = __builtin_amdgcn_mfma_f32_16x16x32_bf16(af[m], bfr[n], acc[m][n], 0, 0, 0);
  }

  #pragma unroll
  for (int m = 0; m < 4; ++m) {
    int gr0 = mbase + wrow + m * 16 + (ln >> 4) * 4;
    #pragma unroll
    for (int n = 0; n < 2; ++n) {
      int gcl = wcol + n * 16 + (ln & 15);
      #pragma unroll
      for (int r = 0; r < 4; ++r) {
        int gr = gr0 + r;
        if (gr >= M) continue;
        float v = acc[m][n][r];
        if (bnb == 0) Cb[(size_t)gr * 128 + gcl] = f2b(v);
        else          Cb2[(size_t)gr * 256 + (bnb - 1) * 128 + gcl] = f2b(v);
      }
    }
  }
}

// =====================================================================
// k_attn: edge-softmax attention (fixed-max, packed-f32) FUSED with
// wo-GEMM + LN1. 512 thr / 8 waves / 32 nodes per block; each wave
// serially processes 4 nodes, results -> swizzled LDS tile savt[32][128];
// then ph0-style Wo MFMA (+feat residual) + register-LN1 -> h1b (bf16).
// LDS = savt 8KB + wot 32KB + lnred 2KB = 42KB -> 3 blocks/CU.
// =====================================================================
__global__ __launch_bounds__(512, 2) void k_attn(
    const ushort* __restrict__ q, const ushort* __restrict__ kv,
    const int* __restrict__ off, const int* __restrict__ csr,
    const float* __restrict__ feat, const ushort* __restrict__ wo,
    const float* __restrict__ ln1g, const float* __restrict__ ln1b,
    ushort* __restrict__ h1b, int n)
{
  __shared__ ushort savt[32 * 128];   // 256B rows, 16-chunk XOR swizzle
  __shared__ ushort wot[128 * 128];   // k_mmT Bs layout
  __shared__ float lnred[32 * 16];

  const int tid = threadIdx.x;
  const int wv = tid >> 6, ln = tid & 63;
  const int lr = ln & 15, hi = ln >> 4;
  const int g = ln >> 3, sl = ln & 7;
  const int mbase = blockIdx.x * 32;

  // stage Wo (32KB, completes by the post-attn barrier's vmcnt drain)
  #pragma unroll
  for (int is = 0; is < 4; ++is) {
    int o = is * 8192 + tid * 16;
    int r = o >> 8;
    int c = ((o >> 4) & 15) ^ (r & 15);
    const ushort* s = wo + (size_t)r * 128 + c * 8;
    __builtin_amdgcn_global_load_lds(
        (const __attribute__((address_space(1))) void*)s,
        (__attribute__((address_space(3))) void*)((char*)wot + is * 8192 + wv * 1024),
        16, 0, 0);
  }

  // ---- attention: wave wv processes nodes mbase + wv*4 + i ----
  for (int i = 0; i < 4; ++i) {
    int node = mbase + wv * 4 + i;
    if (node < n) {
      const ushort* qr = q + (size_t)node * 128 + sl * 16;
      uint4 qw0 = *reinterpret_cast<const uint4*>(qr);
      uint4 qw1 = *reinterpret_cast<const uint4*>(qr + 8);
      f32x2 qv[8];
      qv[0] = upk2(qw0.x); qv[1] = upk2(qw0.y); qv[2] = upk2(qw0.z); qv[3] = upk2(qw0.w);
      qv[4] = upk2(qw1.x); qv[5] = upk2(qw1.y); qv[6] = upk2(qw1.z); qv[7] = upk2(qw1.w);

      int b = off[node], e = off[node + 1];
      float s = 0.f;
      f32x2 a2[8] = {};
      int nIt = (e - b + 7) >> 3;
      int idx = b + g;
      int sn = (b < e) ? csr[min(idx, e - 1)] : 0;

      for (int it = 0; it < nIt; ++it) {
        bool act = idx < e;
        const ushort* kr = kv + (size_t)sn * 256 + sl * 16;
        uint4 kw0 = *reinterpret_cast<const uint4*>(kr);
        uint4 kw1 = *reinterpret_cast<const uint4*>(kr + 8);
        uint4 vw0 = *reinterpret_cast<const uint4*>(kr + 128);
        uint4 vw1 = *reinterpret_cast<const uint4*>(kr + 136);
        idx += 8;
        if (it + 1 < nIt) sn = csr[min(idx, e - 1)];

        f32x2 acc = qv[0] * upk2(kw0.x);
        acc += qv[1] * upk2(kw0.y);
        acc += qv[2] * upk2(kw0.z);
        acc += qv[3] * upk2(kw0.w);
        acc += qv[4] * upk2(kw1.x);
        acc += qv[5] * upk2(kw1.y);
        acc += qv[6] * upk2(kw1.z);
        acc += qv[7] * upk2(kw1.w);
        float p = acc[0] + acc[1];
        float u = fminf(fmaxf(p * 0.25f, -CLAMP_V), CLAMP_V);
        float w = __expf(u - CLAMP_V);
        w = act ? w : 0.f;
        s += w;
        f32x2 w2v; w2v[0] = w; w2v[1] = w;
        a2[0] += w2v * upk2(vw0.x);
        a2[1] += w2v * upk2(vw0.y);
        a2[2] += w2v * upk2(vw0.z);
        a2[3] += w2v * upk2(vw0.w);
        a2[4] += w2v * upk2(vw1.x);
        a2[5] += w2v * upk2(vw1.y);
        a2[6] += w2v * upk2(vw1.z);
        a2[7] += w2v * upk2(vw1.w);
      }

      #pragma unroll
      for (int msk = 8; msk <= 32; msk <<= 1) {
        s += __shfl_xor(s, msk);
        #pragma unroll
        for (int j = 0; j < 8; ++j) {
          a2[j][0] += __shfl_xor(a2[j][0], msk);
          a2[j][1] += __shfl_xor(a2[j][1], msk);
        }
      }

      float inv = (s > 0.f) ? 1.f / s : 0.f;
      if (g == 0) {
        uint w[8];
        #pragma unroll
        for (int j = 0; j < 8; ++j)
          w[j] = (uint)f2b(a2[j][0] * inv) | ((uint)f2b(a2[j][1] * inv) << 16);
        int nl = wv * 4 + i;
        int c0 = sl * 2, c1 = sl * 2 + 1;
        uint4 o0 = {w[0], w[1], w[2], w[3]};
        uint4 o1 = {w[4], w[5], w[6], w[7]};
        *reinterpret_cast<uint4*>((char*)savt + nl * 256 + ((c0 ^ (nl & 15)) << 4)) = o0;
        *reinterpret_cast<uint4*>((char*)savt + nl * 256 + ((c1 ^ (nl & 15)) << 4)) = o1;
      }
    }
  }
  __syncthreads();   // savt complete; wot DMA drained

  // ---- Wo GEMM [32][128]: h1 = LN1(savt @ Wo^T + feat) ----
  const int gc = wv * 16 + lr;
  f32x4 p0[2] = {};
  #pragma unroll
  for (int kk = 0; kk < 4; ++kk) {
    int c = kk * 4 + hi;
    int wr = wv * 16 + lr;
    bf16x8 bWo = *reinterpret_cast<const bf16x8*>((char*)wot + wr * 256 + ((c ^ (wr & 15)) << 4));
    bf16x8 aS[2];
    #pragma unroll
    for (int m = 0; m < 2; ++m) {
      int r = m * 16 + lr;
      aS[m] = *reinterpret_cast<const bf16x8*>((char*)savt + r * 256 + ((c ^ (r & 15)) << 4));
    }
    #pragma unroll
    for (int m = 0; m < 2; ++m)
      p0[m] = __builtin_amdgcn_mfma_f32_16x16x32_bf16(aS[m], bWo, p0[m], 0, 0, 0);
  }
  // +feat residual
  #pragma unroll
  for (int m = 0; m < 2; ++m)
    #pragma unroll
    for (int r = 0; r < 4; ++r) {
      int gr = mbase + m * 16 + hi * 4 + r;
      p0[m][r] += feat[(size_t)min(gr, n - 1) * 128 + gc];
    }
  // LN1
  #pragma unroll
  for (int m = 0; m < 2; ++m)
    #pragma unroll
    for (int r = 0; r < 4; ++r) {
      float sm = p0[m][r];
      float sq = p0[m][r] * p0[m][r];
      #pragma unroll
      for (int msk = 1; msk <= 8; msk <<= 1) {
        sm += __shfl_xor(sm, msk);
        sq += __shfl_xor(sq, msk);
      }
      if (lr == 0) {
        int row = m * 16 + hi * 4 + r;
        lnred[row * 16 + wv * 2]     = sm;
        lnred[row * 16 + wv * 2 + 1] = sq;
      }
    }
  __syncthreads();
  {
    float g1v = ln1g[gc], bb1 = ln1b[gc];
    #pragma unroll
    for (int m = 0; m < 2; ++m)
      #pragma unroll
      for (int r = 0; r < 4; ++r) {
        int row = m * 16 + hi * 4 + r;
        int gr = mbase + row;
        float sm = 0.f, sq = 0.f;
        #pragma unroll
        for (int w = 0; w < 8; ++w) {
          sm += lnred[row * 16 + w * 2];
          sq += lnred[row * 16 + w * 2 + 1];
        }
        float mu = sm * (1.f / 128.f);
        float var = fmaxf(sq * (1.f / 128.f) - mu * mu, 0.f);
        float rstd = rsqrtf(var + LN_EPS);
        if (gr < n)
          h1b[(size_t)gr * 128 + gc] = f2b((p0[m][r] - mu) * rstd * g1v + bb1);
      }
  }
}

// =====================================================================
// k_ffn: 32 rows/block, 66KB LDS -> 2 blocks/CU (round-16 proven).
// =====================================================================
__global__ __launch_bounds__(512, 4) void k_ffn(
    const ushort* __restrict__ h1b,
    const ushort* __restrict__ w1, const float* __restrict__ b1,
    const ushort* __restrict__ w2, const float* __restrict__ b2,
    const float* __restrict__ lng, const float* __restrict__ lnbv,
    float* __restrict__ outp, int M)
{
  __shared__ ushort mid[32 * 512];
  __shared__ ushort wbuf[2][128 * 64];
  __shared__ float lnred[32 * 16];

  const int tid = threadIdx.x;
  const int wv = tid >> 6, ln = tid & 63;
  const int lr = ln & 15, hi = ln >> 4;
  const int mbase = blockIdx.x * 32;
  const int gc = wv * 16 + lr;

  auto STG64 = [&](const ushort* srcBase, int srcLd, int colOff, char* dstLds) {
    #pragma unroll
    for (int is = 0; is < 2; ++is) {
      int o = is * 8192 + tid * 16;
      int r = o >> 7;
      int c = ((o >> 4) & 7) ^ (r & 7);
      const ushort* s = srcBase + (size_t)r * srcLd + colOff + c * 8;
      __builtin_amdgcn_global_load_lds(
          (const __attribute__((address_space(1))) void*)s,
          (__attribute__((address_space(3))) void*)(dstLds + is * 8192 + wv * 1024),
          16, 0, 0);
    }
  };

  {
    int o = tid * 16;
    int r = o >> 8;
    int c = ((o >> 4) & 15) ^ (r & 15);
    int gr = min(mbase + r, M - 1);
    const ushort* s = h1b + (size_t)gr * 128 + c * 8;
    __builtin_amdgcn_global_load_lds(
        (const __attribute__((address_space(1))) void*)s,
        (__attribute__((address_space(3))) void*)((char*)mid + wv * 1024),
        16, 0, 0);
  }
  STG64(w1, 128, 0, (char*)wbuf[0]);
  __syncthreads();

  f32x4 p1[4][2] = {};
  const char* hB = (const char*)mid;
  #pragma unroll
  for (int g = 0; g < 4; ++g) {
    #pragma unroll
    for (int kh = 0; kh < 2; ++kh) {
      const int step = g * 2 + kh;
      if (step < 7) {
        int ns = step + 1;
        STG64(w1 + (size_t)(ns >> 1) * 128 * 128, 128, (ns & 1) * 64, (char*)wbuf[ns & 1]);
      } else {
        STG64(w2, 512, 0, (char*)wbuf[0]);
      }
      const char* wB = (const char*)wbuf[step & 1];
      #pragma unroll
      for (int kk = 0; kk < 2; ++kk) {
        int ct = kk * 4 + hi;
        int cg = kh * 8 + ct;
        int wr = wv * 16 + lr;
        bf16x8 aW = *reinterpret_cast<const bf16x8*>(wB + wr * 128 + ((ct ^ (wr & 7)) << 4));
        bf16x8 bH[2];
        #pragma unroll
        for (int hj = 0; hj < 2; ++hj) {
          int r = hj * 16 + lr;
          bH[hj] = *reinterpret_cast<const bf16x8*>(hB + r * 256 + ((cg ^ (r & 15)) << 4));
        }
        #pragma unroll
        for (int hj = 0; hj < 2; ++hj)
          p1[g][hj] = __builtin_amdgcn_mfma_f32_16x16x32_bf16(aW, bH[hj], p1[g][hj], 0, 0, 0);
      }
      __syncthreads();
    }
  }

  float h1res[2][4];
  {
    int chunk = gc >> 3;
    int sub = (gc & 7) * 2;
    #pragma unroll
    for (int m = 0; m < 2; ++m)
      #pragma unroll
      for (int r = 0; r < 4; ++r) {
        int row = m * 16 + hi * 4 + r;
        h1res[m][r] = b2f(*reinterpret_cast<const ushort*>(
            (const char*)mid + row * 256 + ((chunk ^ (row & 15)) << 4) + sub));
      }
  }
  __syncthreads();

  #pragma unroll
  for (int g = 0; g < 4; ++g) {
    int mc0 = g * 128 + wv * 16 + hi * 4;
    float4 bv = *reinterpret_cast<const float4*>(b1 + mc0);
    int chunk = mc0 >> 3;
    int sub = (mc0 & 7) * 2;
    #pragma unroll
    for (int hj = 0; hj < 2; ++hj) {
      int orow = hj * 16 + lr;
      ushort4 pk;
      pk.x = f2b(fmaxf(p1[g][hj][0] + bv.x, 0.f));
      pk.y = f2b(fmaxf(p1[g][hj][1] + bv.y, 0.f));
      pk.z = f2b(fmaxf(p1[g][hj][2] + bv.z, 0.f));
      pk.w = f2b(fmaxf(p1[g][hj][3] + bv.w, 0.f));
      char* dstp = (char*)mid + orow * 1024 + (((chunk & 63) ^ (orow & 15)) << 4) + sub;
      *reinterpret_cast<ushort4*>(dstp) = pk;
    }
  }
  __syncthreads();

  f32x4 p2[2] = {};
  #pragma unroll
  for (int kt = 0; kt < 8; ++kt) {
    if (kt < 7) STG64(w2, 512, (kt + 1) * 64, (char*)wbuf[(kt + 1) & 1]);
    const char* wB = (const char*)wbuf[kt & 1];
    #pragma unroll
    for (int kk = 0; kk < 2; ++kk) {
      int ct = kk * 4 + hi;
      int cm = kt * 8 + ct;
      int wr = wv * 16 + lr;
      bf16x8 bW = *reinterpret_cast<const bf16x8*>(wB + wr * 128 + ((ct ^ (wr & 7)) << 4));
      bf16x8 aM[2];
      #pragma unroll
      for (int m = 0; m < 2; ++m) {
        int r = m * 16 + lr;
        aM[m] = *reinterpret_cast<const bf16x8*>((const char*)mid + r * 1024 + (((cm & 63) ^ (r & 15)) << 4));
      }
      #pragma unroll
      for (int m = 0; m < 2; ++m)
        p2[m] = __builtin_amdgcn_mfma_f32_16x16x32_bf16(aM[m], bW, p2[m], 0, 0, 0);
    }
    __syncthreads();
  }

  {
    float bsv = b2[gc];
    #pragma unroll
    for (int m = 0; m < 2; ++m)
      #pragma unroll
      for (int r = 0; r < 4; ++r)
        p2[m][r] += bsv + h1res[m][r];
  }
  #pragma unroll
  for (int m = 0; m < 2; ++m)
    #pragma unroll
    for (int r = 0; r < 4; ++r) {
      float sm = p2[m][r];
      float sq = p2[m][r] * p2[m][r];
      #pragma unroll
      for (int msk = 1; msk <= 8; msk <<= 1) {
        sm += __shfl_xor(sm, msk);
        sq += __shfl_xor(sq, msk);
      }
      if (lr == 0) {
        int row = m * 16 + hi * 4 + r;
        lnred[row * 16 + wv * 2]     = sm;
        lnred[row * 16 + wv * 2 + 1] = sq;
      }
    }
  __syncthreads();
  {
    float g2v = lng[gc], bb2 = lnbv[gc];
    #pragma unroll
    for (int m = 0; m < 2; ++m)
      #pragma unroll
      for (int r = 0; r < 4; ++r) {
        int row = m * 16 + hi * 4 + r;
        int gr = mbase + row;
        float sm = 0.f, sq = 0.f;
        #pragma unroll
        for (int w = 0; w < 8; ++w) {
          sm += lnred[row * 16 + w * 2];
          sq += lnred[row * 16 + w * 2 + 1];
        }
        float mu = sm * (1.f / 128.f);
        float var = fmaxf(sq * (1.f / 128.f) - mu * mu, 0.f);
        float rstd = rsqrtf(var + LN_EPS);
        if (gr < M)
          outp[(size_t)gr * 128 + gc] = (p2[m][r] - mu) * rstd * g2v + bb2;
      }
  }
}

extern "C" void kernel_launch(void* const* d_in, const int* in_sizes, int n_in,
                              void* d_out, int out_size, void* d_ws, size_t ws_size,
                              hipStream_t stream)
{
  const float* feat = (const float*)d_in[0];
  const int*   src  = (const int*)d_in[1];
  const int*   dst  = (const int*)d_in[2];
  const float* Wq   = (const float*)d_in[3];
  const float* Wk   = (const float*)d_in[4];
  const float* Wv   = (const float*)d_in[5];
  const float* Wo   = (const float*)d_in[6];
  const float* ln1g = (const float*)d_in[7];
  const float* ln1b = (const float*)d_in[8];
  const float* W1   = (const float*)d_in[9];
  const float* b1   = (const float*)d_in[10];
  const float* W2   = (const float*)d_in[11];
  const float* b2   = (const float*)d_in[12];
  const float* ln2g = (const float*)d_in[13];
  const float* ln2b = (const float*)d_in[14];
  float* out = (float*)d_out;

  const int N = in_sizes[0] / DM;
  const int E = in_sizes[1];
  const size_t NB = (size_t)N;

  char* wsb = (char*)d_ws;
  ushort* q_bf    = (ushort*)wsb;
  ushort* kv_bf   = (ushort*)(wsb + NB * 256);
  ushort* h1b     = (ushort*)(wsb + NB * 1536);
  ushort* feat_bf = (ushort*)(wsb + NB * 1792);
  ushort* wbf     = (ushort*)(wsb + NB * 2048);
  ushort* wqkv_bf = wbf;
  ushort* wo_bf   = wbf + 49152;
  ushort* w1_bf   = wbf + 65536;
  ushort* w2_bf   = wbf + 131072;
  int* ib  = (int*)(wbf + 196608);
  int* deg = ib;
  int* cur = ib + N;
  int* off = ib + 2 * N;
  int* csr = ib + 3 * N + 1;

  hipMemsetAsync(deg, 0, (size_t)N * sizeof(int), stream);

  int nf4 = N * DM / 4;
  int castBlocks = (nf4 + 49152 + 255) / 256;
  int cntBlocks = (E + 255) / 256;
  k_prep<<<castBlocks + cntBlocks, 256, 0, stream>>>(
      feat, Wq, Wk, Wv, Wo, W1, W2, feat_bf, wbf, dst, deg, nf4, castBlocks, E);

  int nbk = (N + SC_EPB - 1) / SC_EPB;
  k_scan<<<nbk, 256, 0, stream>>>(deg, off, cur, N, E);
  k_scatter<<<cntBlocks, 256, 0, stream>>>(src, dst, off, cur, csr, E);

  const int nT = (N + 127) / 128;   // 313
  k_qkv<<<dim3(3, nT), 512, 0, stream>>>(feat_bf, wqkv_bf, q_bf, kv_bf, N);

  // attn + wo + LN1 fused -> h1b
  const int nA = (N + 31) / 32;     // 1250
  k_attn<<<nA, 512, 0, stream>>>(
      q_bf, kv_bf, off, csr, feat, wo_bf, ln1g, ln1b, h1b, N);

  // fused FFN: out = LN2(relu(h1b@W1^T+b1)@W2^T + b2 + h1res)
  const int nF = (N + 31) / 32;     // 1250
  k_ffn<<<nF, 512, 0, stream>>>(
      h1b, w1_bf, b1, w2_bf, b2, ln2g, ln2b, out, N);
}

// Round 19
// 187.193 us; speedup vs baseline: 1.0133x; 1.0133x over previous
//
#include <hip/hip_runtime.h>

#define DM 128
#define DFF 512
#define CLAMP_V 5.0f
#define LN_EPS 1e-5f

typedef __attribute__((ext_vector_type(8))) short bf16x8;
typedef __attribute__((ext_vector_type(4))) float f32x4;
typedef __attribute__((ext_vector_type(2))) float f32x2;

__device__ __forceinline__ float b2f(ushort u) {
  union { uint u; float f; } x; x.u = ((uint)u) << 16; return x.f;
}
__device__ __forceinline__ ushort f2b(float f) {
  union { float f; uint u; } x; x.f = f;
  uint r = x.u + 0x7FFFu + ((x.u >> 16) & 1u);
  return (ushort)(r >> 16);
}
__device__ __forceinline__ f32x2 upk2(uint w) {
  union { uint u; float f; } a, b;
  a.u = w << 16; b.u = w & 0xFFFF0000u;
  f32x2 r; r[0] = a.f; r[1] = b.f; return r;
}

// ---------------- fused prep: feat cast + weight cast + degree count ----------------
__global__ void k_prep(const float* __restrict__ feat,
                       const float* __restrict__ wq, const float* __restrict__ wk,
                       const float* __restrict__ wv, const float* __restrict__ wo,
                       const float* __restrict__ w1, const float* __restrict__ w2,
                       ushort* __restrict__ feat_bf, ushort* __restrict__ wbf,
                       const int* __restrict__ dst, int* __restrict__ deg,
                       int nf4, int castBlocks, int E) {
  if ((int)blockIdx.x >= castBlocks) {
    int e = ((int)blockIdx.x - castBlocks) * 256 + threadIdx.x;
    if (e < E) atomicAdd(&deg[dst[e]], 1);
    return;
  }
  int i = blockIdx.x * 256 + threadIdx.x;
  if (i < nf4) {
    float4 v = *reinterpret_cast<const float4*>(feat + i * 4);
    ushort4 o; o.x = f2b(v.x); o.y = f2b(v.y); o.z = f2b(v.z); o.w = f2b(v.w);
    *reinterpret_cast<ushort4*>(feat_bf + i * 4) = o;
    return;
  }
  int i4 = (i - nf4) * 4;
  if (i4 >= 196608) return;
  const float* s; int o;
  if      (i4 < 16384)  { s = wq; o = i4; }
  else if (i4 < 32768)  { s = wk; o = i4 - 16384; }
  else if (i4 < 49152)  { s = wv; o = i4 - 32768; }
  else if (i4 < 65536)  { s = wo; o = i4 - 49152; }
  else if (i4 < 131072) { s = w1; o = i4 - 65536; }
  else                  { s = w2; o = i4 - 131072; }
  float4 v = *reinterpret_cast<const float4*>(s + o);
  ushort4 u; u.x = f2b(v.x); u.y = f2b(v.y); u.z = f2b(v.z); u.w = f2b(v.w);
  *reinterpret_cast<ushort4*>(wbf + i4) = u;
}

#define SC_EPB 1024

// single-kernel exclusive scan; also zeroes cur, writes off[n]=E
__global__ __launch_bounds__(256) void k_scan(const int* __restrict__ deg,
                                              int* __restrict__ off,
                                              int* __restrict__ cur,
                                              int n, int E) {
  __shared__ int sh[256];
  __shared__ int wsum[4];
  const int t = threadIdx.x;
  const int bstart = blockIdx.x * SC_EPB;

  int gs = 0;
  for (int base = t * 4; base < bstart; base += SC_EPB) {
    int4 v = *reinterpret_cast<const int4*>(deg + base);
    gs += v.x + v.y + v.z + v.w;
  }
  #pragma unroll
  for (int m = 1; m < 64; m <<= 1) gs += __shfl_xor(gs, m);
  if ((t & 63) == 0) wsum[t >> 6] = gs;
  __syncthreads();
  int gadd = wsum[0] + wsum[1] + wsum[2] + wsum[3];
  __syncthreads();

  int base = bstart + t * 4;
  int4 v = {0, 0, 0, 0};
  if (base + 3 < n) {
    v = *reinterpret_cast<const int4*>(deg + base);
  } else {
    if (base     < n) v.x = deg[base];
    if (base + 1 < n) v.y = deg[base + 1];
    if (base + 2 < n) v.z = deg[base + 2];
    if (base + 3 < n) v.w = deg[base + 3];
  }
  int s = v.x + v.y + v.z + v.w;
  sh[t] = s;
  __syncthreads();
  #pragma unroll
  for (int d = 1; d < 256; d <<= 1) {
    int x = 0;
    if (t >= d) x = sh[t - d];
    __syncthreads();
    sh[t] += x;
    __syncthreads();
  }
  int ex = sh[t] - s + gadd;
  if (base + 3 < n) {
    int4 o; o.x = ex; o.y = ex + v.x; o.z = ex + v.x + v.y; o.w = ex + v.x + v.y + v.z;
    *reinterpret_cast<int4*>(off + base) = o;
    int4 z = {0, 0, 0, 0};
    *reinterpret_cast<int4*>(cur + base) = z;
  } else {
    if (base     < n) { off[base]     = ex;                    cur[base]     = 0; }
    if (base + 1 < n) { off[base + 1] = ex + v.x;              cur[base + 1] = 0; }
    if (base + 2 < n) { off[base + 2] = ex + v.x + v.y;        cur[base + 2] = 0; }
    if (base + 3 < n) { off[base + 3] = ex + v.x + v.y + v.z;  cur[base + 3] = 0; }
  }
  if (blockIdx.x == 0 && t == 0) off[n] = E;
}

// standalone scatter (0 LDS, full occupancy)
__global__ void k_scatter(const int* __restrict__ src, const int* __restrict__ dst,
                          const int* __restrict__ off, int* __restrict__ cur,
                          int* __restrict__ csr, int E) {
  int e = blockIdx.x * blockDim.x + threadIdx.x;
  if (e < E) {
    int d = dst[e];
    int p = off[d] + atomicAdd(&cur[d], 1);
    csr[p] = src[e];
  }
}

// =====================================================================
// k_qkv: one-tile-per-block GEMM, QKV split output. 512 thr, 2 blk/CU.
// =====================================================================
__global__ __launch_bounds__(512, 2) void k_qkv(
    const ushort* __restrict__ A, const ushort* __restrict__ W,
    ushort* __restrict__ Cb, ushort* __restrict__ Cb2, int M)
{
  __shared__ ushort As[128 * 128];
  __shared__ ushort Bs[128 * 128];

  const int tid = threadIdx.x;
  const int wv = tid >> 6, ln = tid & 63;
  const int bnb = blockIdx.x;
  const int mbase = blockIdx.y * 128;
  const int wrow = (wv >> 2) * 64, wcol = (wv & 3) * 32;
  const int o_base = tid * 16;

  #pragma unroll
  for (int is = 0; is < 4; ++is) {
    int o = is * 8192 + o_base;
    int row = o >> 8;
    int c = ((o >> 4) & 15) ^ (row & 15);
    int gr = min(mbase + row, M - 1);
    const ushort* sA = A + (size_t)gr * 128 + c * 8;
    __builtin_amdgcn_global_load_lds(
        (const __attribute__((address_space(1))) void*)sA,
        (__attribute__((address_space(3))) void*)((char*)As + is * 8192 + wv * 1024),
        16, 0, 0);
    const ushort* sB = W + (size_t)(bnb * 128 + row) * 128 + c * 8;
    __builtin_amdgcn_global_load_lds(
        (const __attribute__((address_space(1))) void*)sB,
        (__attribute__((address_space(3))) void*)((char*)Bs + is * 8192 + wv * 1024),
        16, 0, 0);
  }
  __syncthreads();

  f32x4 acc[4][2] = {};
  const char* AsB = (const char*)As;
  const char* BsB = (const char*)Bs;
  #pragma unroll
  for (int kk = 0; kk < 4; ++kk) {
    bf16x8 af[4], bfr[2];
    #pragma unroll
    for (int m = 0; m < 4; ++m) {
      int r = wrow + m * 16 + (ln & 15);
      int c = kk * 4 + (ln >> 4);
      af[m] = *reinterpret_cast<const bf16x8*>(AsB + r * 256 + ((c ^ (r & 15)) << 4));
    }
    #pragma unroll
    for (int n = 0; n < 2; ++n) {
      int r = wcol + n * 16 + (ln & 15);
      int c = kk * 4 + (ln >> 4);
      bfr[n] = *reinterpret_cast<const bf16x8*>(BsB + r * 256 + ((c ^ (r & 15)) << 4));
    }
    #pragma unroll
    for (int m = 0; m < 4; ++m)
      #pragma unroll
      for (int n = 0; n < 2; ++n)
        acc[m][n] = __builtin_amdgcn_mfma_f32_16x16x32_bf16(af[m], bfr[n], acc[m][n], 0, 0, 0);
  }

  #pragma unroll
  for (int m = 0; m < 4; ++m) {
    int gr0 = mbase + wrow + m * 16 + (ln >> 4) * 4;
    #pragma unroll
    for (int n = 0; n < 2; ++n) {
      int gcl = wcol + n * 16 + (ln & 15);
      #pragma unroll
      for (int r = 0; r < 4; ++r) {
        int gr = gr0 + r;
        if (gr >= M) continue;
        float v = acc[m][n][r];
        if (bnb == 0) Cb[(size_t)gr * 128 + gcl] = f2b(v);
        else          Cb2[(size_t)gr * 256 + (bnb - 1) * 128 + gcl] = f2b(v);
      }
    }
  }
}

// =====================================================================
// k_attn: attn + wo + LN1 fused. 16 nodes/block, 8 waves; wave handles
// 2 nodes serially (half of round-18's 4). LDS = savt 4KB + wot 32KB +
// lnred 1KB = 37KB -> 3 blocks/CU (launch_bounds(512,3), 24 waves/CU).
// =====================================================================
__global__ __launch_bounds__(512, 3) void k_attn(
    const ushort* __restrict__ q, const ushort* __restrict__ kv,
    const int* __restrict__ off, const int* __restrict__ csr,
    const float* __restrict__ feat, const ushort* __restrict__ wo,
    const float* __restrict__ ln1g, const float* __restrict__ ln1b,
    ushort* __restrict__ h1b, int n)
{
  __shared__ ushort savt[16 * 128];   // 256B rows, 16-chunk XOR swizzle
  __shared__ ushort wot[128 * 128];   // k_mmT Bs layout
  __shared__ float lnred[16 * 16];

  const int tid = threadIdx.x;
  const int wv = tid >> 6, ln = tid & 63;
  const int lr = ln & 15, hi = ln >> 4;
  const int g = ln >> 3, sl = ln & 7;
  const int mbase = blockIdx.x * 16;

  // stage Wo (32KB; drained by the post-attn barrier)
  #pragma unroll
  for (int is = 0; is < 4; ++is) {
    int o = is * 8192 + tid * 16;
    int r = o >> 8;
    int c = ((o >> 4) & 15) ^ (r & 15);
    const ushort* s = wo + (size_t)r * 128 + c * 8;
    __builtin_amdgcn_global_load_lds(
        (const __attribute__((address_space(1))) void*)s,
        (__attribute__((address_space(3))) void*)((char*)wot + is * 8192 + wv * 1024),
        16, 0, 0);
  }

  // ---- attention: wave wv processes nodes mbase + wv*2 + {0,1} ----
  #pragma unroll
  for (int i = 0; i < 2; ++i) {
    int node = mbase + wv * 2 + i;
    if (node < n) {
      const ushort* qr = q + (size_t)node * 128 + sl * 16;
      uint4 qw0 = *reinterpret_cast<const uint4*>(qr);
      uint4 qw1 = *reinterpret_cast<const uint4*>(qr + 8);
      f32x2 qv[8];
      qv[0] = upk2(qw0.x); qv[1] = upk2(qw0.y); qv[2] = upk2(qw0.z); qv[3] = upk2(qw0.w);
      qv[4] = upk2(qw1.x); qv[5] = upk2(qw1.y); qv[6] = upk2(qw1.z); qv[7] = upk2(qw1.w);

      int b = off[node], e = off[node + 1];
      float s = 0.f;
      f32x2 a2[8] = {};
      int nIt = (e - b + 7) >> 3;
      int idx = b + g;
      int sn = (b < e) ? csr[min(idx, e - 1)] : 0;

      for (int it = 0; it < nIt; ++it) {
        bool act = idx < e;
        const ushort* kr = kv + (size_t)sn * 256 + sl * 16;
        uint4 kw0 = *reinterpret_cast<const uint4*>(kr);
        uint4 kw1 = *reinterpret_cast<const uint4*>(kr + 8);
        uint4 vw0 = *reinterpret_cast<const uint4*>(kr + 128);
        uint4 vw1 = *reinterpret_cast<const uint4*>(kr + 136);
        idx += 8;
        if (it + 1 < nIt) sn = csr[min(idx, e - 1)];

        f32x2 acc = qv[0] * upk2(kw0.x);
        acc += qv[1] * upk2(kw0.y);
        acc += qv[2] * upk2(kw0.z);
        acc += qv[3] * upk2(kw0.w);
        acc += qv[4] * upk2(kw1.x);
        acc += qv[5] * upk2(kw1.y);
        acc += qv[6] * upk2(kw1.z);
        acc += qv[7] * upk2(kw1.w);
        float p = acc[0] + acc[1];
        float u = fminf(fmaxf(p * 0.25f, -CLAMP_V), CLAMP_V);
        float w = __expf(u - CLAMP_V);
        w = act ? w : 0.f;
        s += w;
        f32x2 w2v; w2v[0] = w; w2v[1] = w;
        a2[0] += w2v * upk2(vw0.x);
        a2[1] += w2v * upk2(vw0.y);
        a2[2] += w2v * upk2(vw0.z);
        a2[3] += w2v * upk2(vw0.w);
        a2[4] += w2v * upk2(vw1.x);
        a2[5] += w2v * upk2(vw1.y);
        a2[6] += w2v * upk2(vw1.z);
        a2[7] += w2v * upk2(vw1.w);
      }

      #pragma unroll
      for (int msk = 8; msk <= 32; msk <<= 1) {
        s += __shfl_xor(s, msk);
        #pragma unroll
        for (int j = 0; j < 8; ++j) {
          a2[j][0] += __shfl_xor(a2[j][0], msk);
          a2[j][1] += __shfl_xor(a2[j][1], msk);
        }
      }

      float inv = (s > 0.f) ? 1.f / s : 0.f;
      if (g == 0) {
        uint w[8];
        #pragma unroll
        for (int j = 0; j < 8; ++j)
          w[j] = (uint)f2b(a2[j][0] * inv) | ((uint)f2b(a2[j][1] * inv) << 16);
        int nl = wv * 2 + i;
        int c0 = sl * 2, c1 = sl * 2 + 1;
        uint4 o0 = {w[0], w[1], w[2], w[3]};
        uint4 o1 = {w[4], w[5], w[6], w[7]};
        *reinterpret_cast<uint4*>((char*)savt + nl * 256 + ((c0 ^ (nl & 15)) << 4)) = o0;
        *reinterpret_cast<uint4*>((char*)savt + nl * 256 + ((c1 ^ (nl & 15)) << 4)) = o1;
      }
    }
  }
  __syncthreads();   // savt complete; wot DMA drained

  // ---- Wo GEMM [16][128]: h1 = LN1(savt @ Wo^T + feat) ----
  const int gc = wv * 16 + lr;
  f32x4 p0 = {};
  #pragma unroll
  for (int kk = 0; kk < 4; ++kk) {
    int c = kk * 4 + hi;
    int wr = wv * 16 + lr;
    bf16x8 bWo = *reinterpret_cast<const bf16x8*>((char*)wot + wr * 256 + ((c ^ (wr & 15)) << 4));
    int r = lr;
    bf16x8 aS = *reinterpret_cast<const bf16x8*>((char*)savt + r * 256 + ((c ^ (r & 15)) << 4));
    p0 = __builtin_amdgcn_mfma_f32_16x16x32_bf16(aS, bWo, p0, 0, 0, 0);
  }
  // +feat residual
  #pragma unroll
  for (int r = 0; r < 4; ++r) {
    int gr = mbase + hi * 4 + r;
    p0[r] += feat[(size_t)min(gr, n - 1) * 128 + gc];
  }
  // LN1 partials
  #pragma unroll
  for (int r = 0; r < 4; ++r) {
    float sm = p0[r];
    float sq = p0[r] * p0[r];
    #pragma unroll
    for (int msk = 1; msk <= 8; msk <<= 1) {
      sm += __shfl_xor(sm, msk);
      sq += __shfl_xor(sq, msk);
    }
    if (lr == 0) {
      int row = hi * 4 + r;
      lnred[row * 16 + wv * 2]     = sm;
      lnred[row * 16 + wv * 2 + 1] = sq;
    }
  }
  __syncthreads();
  {
    float g1v = ln1g[gc], bb1 = ln1b[gc];
    #pragma unroll
    for (int r = 0; r < 4; ++r) {
      int row = hi * 4 + r;
      int gr = mbase + row;
      float sm = 0.f, sq = 0.f;
      #pragma unroll
      for (int w = 0; w < 8; ++w) {
        sm += lnred[row * 16 + w * 2];
        sq += lnred[row * 16 + w * 2 + 1];
      }
      float mu = sm * (1.f / 128.f);
      float var = fmaxf(sq * (1.f / 128.f) - mu * mu, 0.f);
      float rstd = rsqrtf(var + LN_EPS);
      if (gr < n)
        h1b[(size_t)gr * 128 + gc] = f2b((p0[r] - mu) * rstd * g1v + bb1);
    }
  }
}

// =====================================================================
// k_ffn: 32 rows/block, 66KB LDS -> 2 blocks/CU (round-16 proven).
// =====================================================================
__global__ __launch_bounds__(512, 4) void k_ffn(
    const ushort* __restrict__ h1b,
    const ushort* __restrict__ w1, const float* __restrict__ b1,
    const ushort* __restrict__ w2, const float* __restrict__ b2,
    const float* __restrict__ lng, const float* __restrict__ lnbv,
    float* __restrict__ outp, int M)
{
  __shared__ ushort mid[32 * 512];
  __shared__ ushort wbuf[2][128 * 64];
  __shared__ float lnred[32 * 16];

  const int tid = threadIdx.x;
  const int wv = tid >> 6, ln = tid & 63;
  const int lr = ln & 15, hi = ln >> 4;
  const int mbase = blockIdx.x * 32;
  const int gc = wv * 16 + lr;

  auto STG64 = [&](const ushort* srcBase, int srcLd, int colOff, char* dstLds) {
    #pragma unroll
    for (int is = 0; is < 2; ++is) {
      int o = is * 8192 + tid * 16;
      int r = o >> 7;
      int c = ((o >> 4) & 7) ^ (r & 7);
      const ushort* s = srcBase + (size_t)r * srcLd + colOff + c * 8;
      __builtin_amdgcn_global_load_lds(
          (const __attribute__((address_space(1))) void*)s,
          (__attribute__((address_space(3))) void*)(dstLds + is * 8192 + wv * 1024),
          16, 0, 0);
    }
  };

  {
    int o = tid * 16;
    int r = o >> 8;
    int c = ((o >> 4) & 15) ^ (r & 15);
    int gr = min(mbase + r, M - 1);
    const ushort* s = h1b + (size_t)gr * 128 + c * 8;
    __builtin_amdgcn_global_load_lds(
        (const __attribute__((address_space(1))) void*)s,
        (__attribute__((address_space(3))) void*)((char*)mid + wv * 1024),
        16, 0, 0);
  }
  STG64(w1, 128, 0, (char*)wbuf[0]);
  __syncthreads();

  f32x4 p1[4][2] = {};
  const char* hB = (const char*)mid;
  #pragma unroll
  for (int g = 0; g < 4; ++g) {
    #pragma unroll
    for (int kh = 0; kh < 2; ++kh) {
      const int step = g * 2 + kh;
      if (step < 7) {
        int ns = step + 1;
        STG64(w1 + (size_t)(ns >> 1) * 128 * 128, 128, (ns & 1) * 64, (char*)wbuf[ns & 1]);
      } else {
        STG64(w2, 512, 0, (char*)wbuf[0]);
      }
      const char* wB = (const char*)wbuf[step & 1];
      #pragma unroll
      for (int kk = 0; kk < 2; ++kk) {
        int ct = kk * 4 + hi;
        int cg = kh * 8 + ct;
        int wr = wv * 16 + lr;
        bf16x8 aW = *reinterpret_cast<const bf16x8*>(wB + wr * 128 + ((ct ^ (wr & 7)) << 4));
        bf16x8 bH[2];
        #pragma unroll
        for (int hj = 0; hj < 2; ++hj) {
          int r = hj * 16 + lr;
          bH[hj] = *reinterpret_cast<const bf16x8*>(hB + r * 256 + ((cg ^ (r & 15)) << 4));
        }
        #pragma unroll
        for (int hj = 0; hj < 2; ++hj)
          p1[g][hj] = __builtin_amdgcn_mfma_f32_16x16x32_bf16(aW, bH[hj], p1[g][hj], 0, 0, 0);
      }
      __syncthreads();
    }
  }

  float h1res[2][4];
  {
    int chunk = gc >> 3;
    int sub = (gc & 7) * 2;
    #pragma unroll
    for (int m = 0; m < 2; ++m)
      #pragma unroll
      for (int r = 0; r < 4; ++r) {
        int row = m * 16 + hi * 4 + r;
        h1res[m][r] = b2f(*reinterpret_cast<const ushort*>(
            (const char*)mid + row * 256 + ((chunk ^ (row & 15)) << 4) + sub));
      }
  }
  __syncthreads();

  #pragma unroll
  for (int g = 0; g < 4; ++g) {
    int mc0 = g * 128 + wv * 16 + hi * 4;
    float4 bv = *reinterpret_cast<const float4*>(b1 + mc0);
    int chunk = mc0 >> 3;
    int sub = (mc0 & 7) * 2;
    #pragma unroll
    for (int hj = 0; hj < 2; ++hj) {
      int orow = hj * 16 + lr;
      ushort4 pk;
      pk.x = f2b(fmaxf(p1[g][hj][0] + bv.x, 0.f));
      pk.y = f2b(fmaxf(p1[g][hj][1] + bv.y, 0.f));
      pk.z = f2b(fmaxf(p1[g][hj][2] + bv.z, 0.f));
      pk.w = f2b(fmaxf(p1[g][hj][3] + bv.w, 0.f));
      char* dstp = (char*)mid + orow * 1024 + (((chunk & 63) ^ (orow & 15)) << 4) + sub;
      *reinterpret_cast<ushort4*>(dstp) = pk;
    }
  }
  __syncthreads();

  f32x4 p2[2] = {};
  #pragma unroll
  for (int kt = 0; kt < 8; ++kt) {
    if (kt < 7) STG64(w2, 512, (kt + 1) * 64, (char*)wbuf[(kt + 1) & 1]);
    const char* wB = (const char*)wbuf[kt & 1];
    #pragma unroll
    for (int kk = 0; kk < 2; ++kk) {
      int ct = kk * 4 + hi;
      int cm = kt * 8 + ct;
      int wr = wv * 16 + lr;
      bf16x8 bW = *reinterpret_cast<const bf16x8*>(wB + wr * 128 + ((ct ^ (wr & 7)) << 4));
      bf16x8 aM[2];
      #pragma unroll
      for (int m = 0; m < 2; ++m) {
        int r = m * 16 + lr;
        aM[m] = *reinterpret_cast<const bf16x8*>((const char*)mid + r * 1024 + (((cm & 63) ^ (r & 15)) << 4));
      }
      #pragma unroll
      for (int m = 0; m < 2; ++m)
        p2[m] = __builtin_amdgcn_mfma_f32_16x16x32_bf16(aM[m], bW, p2[m], 0, 0, 0);
    }
    __syncthreads();
  }

  {
    float bsv = b2[gc];
    #pragma unroll
    for (int m = 0; m < 2; ++m)
      #pragma unroll
      for (int r = 0; r < 4; ++r)
        p2[m][r] += bsv + h1res[m][r];
  }
  #pragma unroll
  for (int m = 0; m < 2; ++m)
    #pragma unroll
    for (int r = 0; r < 4; ++r) {
      float sm = p2[m][r];
      float sq = p2[m][r] * p2[m][r];
      #pragma unroll
      for (int msk = 1; msk <= 8; msk <<= 1) {
        sm += __shfl_xor(sm, msk);
        sq += __shfl_xor(sq, msk);
      }
      if (lr == 0) {
        int row = m * 16 + hi * 4 + r;
        lnred[row * 16 + wv * 2]     = sm;
        lnred[row * 16 + wv * 2 + 1] = sq;
      }
    }
  __syncthreads();
  {
    float g2v = lng[gc], bb2 = lnbv[gc];
    #pragma unroll
    for (int m = 0; m < 2; ++m)
      #pragma unroll
      for (int r = 0; r < 4; ++r) {
        int row = m * 16 + hi * 4 + r;
        int gr = mbase + row;
        float sm = 0.f, sq = 0.f;
        #pragma unroll
        for (int w = 0; w < 8; ++w) {
          sm += lnred[row * 16 + w * 2];
          sq += lnred[row * 16 + w * 2 + 1];
        }
        float mu = sm * (1.f / 128.f);
        float var = fmaxf(sq * (1.f / 128.f) - mu * mu, 0.f);
        float rstd = rsqrtf(var + LN_EPS);
        if (gr < M)
          outp[(size_t)gr * 128 + gc] = (p2[m][r] - mu) * rstd * g2v + bb2;
      }
  }
}

extern "C" void kernel_launch(void* const* d_in, const int* in_sizes, int n_in,
                              void* d_out, int out_size, void* d_ws, size_t ws_size,
                              hipStream_t stream)
{
  const float* feat = (const float*)d_in[0];
  const int*   src  = (const int*)d_in[1];
  const int*   dst  = (const int*)d_in[2];
  const float* Wq   = (const float*)d_in[3];
  const float* Wk   = (const float*)d_in[4];
  const float* Wv   = (const float*)d_in[5];
  const float* Wo   = (const float*)d_in[6];
  const float* ln1g = (const float*)d_in[7];
  const float* ln1b = (const float*)d_in[8];
  const float* W1   = (const float*)d_in[9];
  const float* b1   = (const float*)d_in[10];
  const float* W2   = (const float*)d_in[11];
  const float* b2   = (const float*)d_in[12];
  const float* ln2g = (const float*)d_in[13];
  const float* ln2b = (const float*)d_in[14];
  float* out = (float*)d_out;

  const int N = in_sizes[0] / DM;
  const int E = in_sizes[1];
  const size_t NB = (size_t)N;

  char* wsb = (char*)d_ws;
  ushort* q_bf    = (ushort*)wsb;
  ushort* kv_bf   = (ushort*)(wsb + NB * 256);
  ushort* h1b     = (ushort*)(wsb + NB * 1536);
  ushort* feat_bf = (ushort*)(wsb + NB * 1792);
  ushort* wbf     = (ushort*)(wsb + NB * 2048);
  ushort* wqkv_bf = wbf;
  ushort* wo_bf   = wbf + 49152;
  ushort* w1_bf   = wbf + 65536;
  ushort* w2_bf   = wbf + 131072;
  int* ib  = (int*)(wbf + 196608);
  int* deg = ib;
  int* cur = ib + N;
  int* off = ib + 2 * N;
  int* csr = ib + 3 * N + 1;

  hipMemsetAsync(deg, 0, (size_t)N * sizeof(int), stream);

  int nf4 = N * DM / 4;
  int castBlocks = (nf4 + 49152 + 255) / 256;
  int cntBlocks = (E + 255) / 256;
  k_prep<<<castBlocks + cntBlocks, 256, 0, stream>>>(
      feat, Wq, Wk, Wv, Wo, W1, W2, feat_bf, wbf, dst, deg, nf4, castBlocks, E);

  int nbk = (N + SC_EPB - 1) / SC_EPB;
  k_scan<<<nbk, 256, 0, stream>>>(deg, off, cur, N, E);
  k_scatter<<<cntBlocks, 256, 0, stream>>>(src, dst, off, cur, csr, E);

  const int nT = (N + 127) / 128;   // 313
  k_qkv<<<dim3(3, nT), 512, 0, stream>>>(feat_bf, wqkv_bf, q_bf, kv_bf, N);

  // attn + wo + LN1 fused -> h1b  (16 nodes/block)
  const int nA = (N + 15) / 16;     // 2500
  k_attn<<<nA, 512, 0, stream>>>(
      q_bf, kv_bf, off, csr, feat, wo_bf, ln1g, ln1b, h1b, N);

  // fused FFN: out = LN2(relu(h1b@W1^T+b1)@W2^T + b2 + h1res)
  const int nF = (N + 31) / 32;     // 1250
  k_ffn<<<nF, 512, 0, stream>>>(
      h1b, w1_bf, b1, w2_bf, b2, ln2g, ln2b, out, N);
}